// Round 6
// baseline (222.747 us; speedup 1.0000x reference)
//
#include <hip/hip_runtime.h>

#define NH 8
#define CDIM 384
#define HDIM 48
#define NTOK 4096
#define PDIM 256
#define BDIM 4

typedef unsigned short u16;
typedef unsigned int u32;
typedef __bf16 bf16x8 __attribute__((ext_vector_type(8)));
typedef float f32x4 __attribute__((ext_vector_type(4)));

__device__ __forceinline__ u16 f2b(float f) {
    u32 u = __float_as_uint(f);
    u = (u + 0x7fffu + ((u >> 16) & 1u)) >> 16;   // RNE bf16
    return (u16)u;
}
__device__ __forceinline__ float b2f(u16 u) {
    return __uint_as_float(((u32)u) << 16);
}

__device__ __forceinline__ bf16x8 bzero8() {
    bf16x8 v;
#pragma unroll
    for (int i = 0; i < 8; i++) v[i] = (__bf16)0.0f;
    return v;
}

__device__ __forceinline__ void gload16(const u16* g, u16* l) {
    __builtin_amdgcn_global_load_lds(
        (const __attribute__((address_space(1))) void*)g,
        (__attribute__((address_space(3))) void*)l, 16, 0, 0);
}

// tanh-form GELU, max abs err ~3e-4 vs exact erf form
__device__ __forceinline__ float gelu_f(float x) {
    float z = 0.7978845608028654f * (x + 0.044715f * x * x * x);
    float e = __expf(2.0f * z);
    float t = 1.0f - 2.0f / (e + 1.0f);
    return 0.5f * x * (1.0f + t);
}

// ---------------------------------------------------------------------------
// Batched transpose + cast: in f32 [Z,R,Cc] -> outT bf16 [Z,Cc,R]
// optional outC bf16 [Z,R,Cc]. block (32,8)
// ---------------------------------------------------------------------------
__global__ __launch_bounds__(256) void transpose_cast(
    const float* __restrict__ in, u16* __restrict__ outT, u16* __restrict__ outC,
    int R, int Cc)
{
    __shared__ float tile[32][33];
    int r0 = blockIdx.y * 32, c0 = blockIdx.x * 32;
    size_t zoff = (size_t)blockIdx.z * R * Cc;
    const float* inp = in + zoff;
    int tx = threadIdx.x, ty = threadIdx.y;
#pragma unroll
    for (int i = 0; i < 4; i++) {
        int r = r0 + ty + i * 8;
        float v = inp[(size_t)r * Cc + c0 + tx];
        tile[ty + i * 8][tx] = v;
        if (outC) outC[zoff + (size_t)r * Cc + c0 + tx] = f2b(v);
    }
    __syncthreads();
    u16* oT = outT + zoff;
#pragma unroll
    for (int i = 0; i < 4; i++) {
        int c = c0 + ty + i * 8;
        oT[(size_t)c * R + r0 + tx] = f2b(tile[tx][ty + i * 8]);
    }
}

// ---------------------------------------------------------------------------
// GEMM: C[M,N] = A[M,K](bf16,row) @ Bt[N,K](bf16,row)^T, f32 accum.
// Tile BMv x 128 (BMv = HALFM?64:128), BK=32, 4 waves, 16x16x32 MFMA.
// 3-deep LDS ring + counted vmcnt (T4): stage(t+2) issued at top of iter t,
// end-of-iter waits vmcnt(LD) so tile t+1 is complete while t+2 stays in
// flight. Raw s_barrier (ONE per K-step); never drain vmcnt(0) mid-loop.
// EPI 0: f32 store to Cf (batch offset bz*sC)
// EPI 1: tanh-gelu(x+bias) -> bf16 Cbf
// EPI 2: x + bias[n] + Yin[b,n,tok] -> f32 Out[b,n,tok], float4 over tok
// EPI 4: split-K partials (bz = b*16+s over K-chunk s of 16)
// EPI 5: bf16-only store to Cbf WITH batch offset bz*sC
// ---------------------------------------------------------------------------
template <int EPI, int HALFM>
__global__ __launch_bounds__(256) void gemm_bt(
    const u16* __restrict__ A, const u16* __restrict__ Bt,
    int M, int Nn, int K, long sA, long sB, long sC,
    float* __restrict__ Cf, const float* __restrict__ bias,
    u16* __restrict__ Cbf, const float* __restrict__ Yin, float* __restrict__ Out)
{
    const int BMv = HALFM ? 64 : 128;
    const int MT  = HALFM ? 2 : 4;
    const int BK = 32, LP = 32;
    __shared__ u16 lsA[3][BMv * LP];
    __shared__ u16 lsB[3][128 * LP];
    const int tid = threadIdx.x;
    const int wave = tid >> 6, lane = tid & 63;
    const int lm = lane & 15, lkb = lane >> 4;
    const int bm = blockIdx.x, bn = blockIdx.y, bz = blockIdx.z;
    int bb = bz, ks = 0, ke = K;
    if (EPI == 4) { bb = bz >> 4; ks = (bz & 15) * (K >> 4); ke = ks + (K >> 4); }
    const u16* Ab = A + (size_t)bb * sA;
    const u16* Bb = Bt + (size_t)bb * sB;
    const int wm = (wave >> 1) * (HALFM ? 32 : 64), wn = (wave & 1) * 64;

    f32x4 acc[MT][4];
#pragma unroll
    for (int i = 0; i < MT; i++)
#pragma unroll
        for (int j = 0; j < 4; j++) acc[i][j] = f32x4{0.f, 0.f, 0.f, 0.f};

    auto stage = [&](int k0, int c) {
        if (HALFM) {
            int cb = wave * 64;
            int q = cb + lane;
            int r = q >> 2, ch = q & 3;
            gload16(Ab + (size_t)(bm * BMv + r) * K + k0 + ch * 8, &lsA[c][cb * 8]);
        } else {
#pragma unroll
            for (int j = 0; j < 2; j++) {
                int cb = (j * 4 + wave) * 64;
                int q = cb + lane;
                int r = q >> 2, ch = q & 3;
                gload16(Ab + (size_t)(bm * BMv + r) * K + k0 + ch * 8, &lsA[c][cb * 8]);
            }
        }
#pragma unroll
        for (int j = 0; j < 2; j++) {
            int cb = (j * 4 + wave) * 64;
            int q = cb + lane;
            int r = q >> 2, ch = q & 3;
            gload16(Bb + (size_t)(bn * 128 + r) * K + k0 + ch * 8, &lsB[c][cb * 8]);
        }
    };
    // loads per stage per thread
    #define WAIT_LD() do { if (HALFM) asm volatile("s_waitcnt vmcnt(3)" ::: "memory"); \
                           else       asm volatile("s_waitcnt vmcnt(4)" ::: "memory"); } while (0)

    const int nt = (ke - ks) / BK;   // all launches have nt >= 8
    stage(ks, 0);
    stage(ks + BK, 1);
    WAIT_LD();                        // tile 0 complete (tile 1 in flight)
    __builtin_amdgcn_s_barrier();
    __builtin_amdgcn_sched_barrier(0);

    for (int t = 0; t < nt; ++t) {
        const int cur = t % 3;
        if (t + 2 < nt) stage(ks + (t + 2) * BK, (t + 2) % 3);
        bf16x8 af[MT], bfr[4];
#pragma unroll
        for (int m = 0; m < MT; m++)
            af[m] = *(const bf16x8*)&lsA[cur][(wm + m * 16 + lm) * LP + lkb * 8];
#pragma unroll
        for (int n = 0; n < 4; n++)
            bfr[n] = *(const bf16x8*)&lsB[cur][(wn + n * 16 + lm) * LP + lkb * 8];
#pragma unroll
        for (int mi = 0; mi < MT; mi++)
#pragma unroll
            for (int ni = 0; ni < 4; ni++)
                acc[mi][ni] = __builtin_amdgcn_mfma_f32_16x16x32_bf16(
                    af[mi], bfr[ni], acc[mi][ni], 0, 0, 0);
        if (t + 1 < nt) {
            __builtin_amdgcn_sched_barrier(0);
            if (t + 2 < nt) { WAIT_LD(); }
            else { asm volatile("s_waitcnt vmcnt(0)" ::: "memory"); }
            __builtin_amdgcn_s_barrier();
            __builtin_amdgcn_sched_barrier(0);
        }
    }
    #undef WAIT_LD

    if (EPI == 2) {
#pragma unroll
        for (int mi = 0; mi < MT; mi++)
#pragma unroll
            for (int ni = 0; ni < 4; ni++) {
                int m0 = bm * BMv + wm + mi * 16 + lkb * 4;
                int n = bn * 128 + wn + ni * 16 + lm;
                int b = m0 >> 12, tok = m0 & 4095;
                size_t oi = ((size_t)b * CDIM + n) * NTOK + tok;
                float4 yv = *(const float4*)(Yin + oi);
                float bv = bias[n];
                float4 ov;
                ov.x = acc[mi][ni][0] + bv + yv.x;
                ov.y = acc[mi][ni][1] + bv + yv.y;
                ov.z = acc[mi][ni][2] + bv + yv.z;
                ov.w = acc[mi][ni][3] + bv + yv.w;
                *(float4*)(Out + oi) = ov;
            }
    } else {
#pragma unroll
        for (int mi = 0; mi < MT; mi++)
#pragma unroll
            for (int ni = 0; ni < 4; ni++)
#pragma unroll
                for (int r = 0; r < 4; r++) {
                    int m = bm * BMv + wm + mi * 16 + lkb * 4 + r;
                    int n = bn * 128 + wn + ni * 16 + lm;
                    float v = acc[mi][ni][r];
                    if (EPI == 0) {
                        Cf[(size_t)bz * sC + (size_t)m * Nn + n] = v;
                    } else if (EPI == 1) {
                        Cbf[(size_t)m * Nn + n] = f2b(gelu_f(v + bias[n]));
                    } else if (EPI == 4) {
                        Cf[(size_t)bz * sC + (size_t)m * Nn + n] = v;
                    } else {  // EPI == 5
                        Cbf[(size_t)bz * sC + (size_t)m * Nn + n] = f2b(v);
                    }
                }
    }
}

// ---------------------------------------------------------------------------
// Reduce 16 split-K slices -> bf16 Gt [B, 256, 384]
// ---------------------------------------------------------------------------
__global__ __launch_bounds__(256) void gred(
    const float* __restrict__ part, u16* __restrict__ Gtb)
{
    int idx = blockIdx.x * 256 + threadIdx.x;      // over B*P*C
    int b = idx / (PDIM * CDIM);
    int e = idx % (PDIM * CDIM);
    float s = 0.f;
#pragma unroll
    for (int j = 0; j < 16; j++)
        s += part[((size_t)(b * 16 + j)) * (PDIM * CDIM) + e];
    Gtb[idx] = f2b(s);
}

// ---------------------------------------------------------------------------
// Column sum-of-squares of q_bf [B,N,C] over N (256-token chunks)
// ---------------------------------------------------------------------------
__global__ __launch_bounds__(128) void colsumsq(
    const u16* __restrict__ q, float* __restrict__ pcs)
{
    int c = blockIdx.x * 128 + threadIdx.x;
    int b = blockIdx.z;
    int chunk = blockIdx.y;
    const u16* qp = q + ((size_t)b * NTOK + chunk * 256) * CDIM + c;
    float s = 0.f;
#pragma unroll 4
    for (int i = 0; i < 256; i++) { float v = b2f(qp[(size_t)i * CDIM]); s += v * v; }
    pcs[(size_t)chunk * (BDIM * CDIM) + b * CDIM + c] = s;
}

__global__ __launch_bounds__(256) void colsumred(
    const float* __restrict__ pcs, float* __restrict__ css)
{
    int idx = blockIdx.x * 256 + threadIdx.x;
    if (idx < BDIM * CDIM) {
        float s = 0.f;
#pragma unroll
        for (int j = 0; j < 16; j++) s += pcs[(size_t)j * (BDIM * CDIM) + idx];
        css[idx] = s;
    }
}

// ---------------------------------------------------------------------------
// From kpvp_t [b, p, 0:384]=kp, [b, p, 384:768]=vp (f32):
// kps [bh, p, d] scaled bf16;  vpb [bh, d, p] bf16
// ---------------------------------------------------------------------------
__global__ __launch_bounds__(256) void scalepack2(
    const float* __restrict__ kpvp, const float* __restrict__ css,
    const float* __restrict__ temp, u16* __restrict__ kps, u16* __restrict__ vpb)
{
    int idx = blockIdx.x * 256 + threadIdx.x;      // over B*P*C
    int c = idx % CDIM;
    int t = idx / CDIM;
    int p = t & 255;
    int b = t >> 8;
    int h = c / HDIM, d = c % HDIM;
    const float* row = kpvp + ((size_t)b * PDIM + p) * (2 * CDIM);
    float kv = row[c];
    float vv = row[CDIM + c];
    float nrm = fmaxf(sqrtf(css[b * CDIM + c]), 1e-12f);
    float sc = temp[h] / nrm;
    int bh = b * NH + h;
    kps[((size_t)bh * PDIM + p) * HDIM + d] = f2b(kv * sc);
    vpb[((size_t)bh * HDIM + d) * PDIM + p] = f2b(vv);
}

// ---------------------------------------------------------------------------
// Fused attention: per (ntile of 64 tokens, h, b).
// ---------------------------------------------------------------------------
__global__ __launch_bounds__(256) void attn_fused(
    const u16* __restrict__ qbf, const u16* __restrict__ kps,
    const u16* __restrict__ vpb, float* __restrict__ o_scr)
{
    __shared__ u16 vp_l[48 * 264];   // [d][p] pad 256->264
    __shared__ u16 un[64 * 264];     // union: kp_l [256][56] then p_l [64][264]
    u16* kp_l = un;
    u16* p_l = un;

    int nt = blockIdx.x, h = blockIdx.y, b = blockIdx.z;
    int tid = threadIdx.x, wave = tid >> 6, lane = tid & 63;
    int lm = lane & 15, lkb = lane >> 4;
    const u16* kpsb = kps + (size_t)(b * NH + h) * PDIM * HDIM;
    const u16* vpbb = vpb + (size_t)(b * NH + h) * HDIM * PDIM;

    for (int i = tid; i < 1536; i += 256) {      // 256 rows x 6 uint4
        int row = i / 6, ch = i % 6;
        *(uint4*)&kp_l[row * 56 + ch * 8] = *(const uint4*)(kpsb + row * 48 + ch * 8);
    }
    for (int i = tid; i < 1536; i += 256) {      // 48 rows x 32 uint4
        int row = i / 32, ch = i % 32;
        *(uint4*)&vp_l[row * 264 + ch * 8] = *(const uint4*)(vpbb + row * 256 + ch * 8);
    }
    __syncthreads();

    int t0 = nt * 64 + wave * 16;
    const u16* qb = qbf + ((size_t)b * NTOK + t0 + lm) * CDIM + h * HDIM;
    bf16x8 a0 = *(const bf16x8*)(qb + lkb * 8);
    bf16x8 a1 = bzero8();
    if (lkb < 2) a1 = *(const bf16x8*)(qb + 32 + lkb * 8);

    f32x4 s[16];
#pragma unroll
    for (int pi = 0; pi < 16; pi++) {
        f32x4 acc = f32x4{0.f, 0.f, 0.f, 0.f};
        bf16x8 b0 = *(const bf16x8*)&kp_l[(pi * 16 + lm) * 56 + lkb * 8];
        acc = __builtin_amdgcn_mfma_f32_16x16x32_bf16(a0, b0, acc, 0, 0, 0);
        bf16x8 b1 = bzero8();
        if (lkb < 2) b1 = *(const bf16x8*)&kp_l[(pi * 16 + lm) * 56 + 32 + lkb * 8];
        acc = __builtin_amdgcn_mfma_f32_16x16x32_bf16(a1, b1, acc, 0, 0, 0);
        s[pi] = acc;
    }
    __syncthreads();   // all QK^T reads of kp_l done before p_l overwrites it

    // softmax over 256 cols
#pragma unroll
    for (int r = 0; r < 4; r++) {
        float mx = s[0][r];
#pragma unroll
        for (int pi = 1; pi < 16; pi++) mx = fmaxf(mx, s[pi][r]);
        for (int m = 1; m < 16; m <<= 1) mx = fmaxf(mx, __shfl_xor(mx, m, 64));
        float e[16];
        float sum = 0.f;
#pragma unroll
        for (int pi = 0; pi < 16; pi++) { e[pi] = __expf(s[pi][r] - mx); sum += e[pi]; }
        for (int m = 1; m < 16; m <<= 1) sum += __shfl_xor(sum, m, 64);
        float inv = 1.0f / sum;
        int tl = wave * 16 + lkb * 4 + r;
#pragma unroll
        for (int pi = 0; pi < 16; pi++)
            p_l[tl * 264 + pi * 16 + lm] = f2b(e[pi] * inv);
    }
    __syncthreads();

    // o = p @ vp^T : per wave 16 tokens x 48 d, K=256
    f32x4 oa[3];
#pragma unroll
    for (int di = 0; di < 3; di++) oa[di] = f32x4{0.f, 0.f, 0.f, 0.f};
#pragma unroll
    for (int ksl = 0; ksl < 8; ksl++) {
        bf16x8 pa = *(const bf16x8*)&p_l[(wave * 16 + lm) * 264 + ksl * 32 + lkb * 8];
#pragma unroll
        for (int di = 0; di < 3; di++) {
            bf16x8 vb = *(const bf16x8*)&vp_l[(di * 16 + lm) * 264 + ksl * 32 + lkb * 8];
            oa[di] = __builtin_amdgcn_mfma_f32_16x16x32_bf16(pa, vb, oa[di], 0, 0, 0);
        }
    }
    size_t obase = (size_t)b * ((size_t)NTOK * CDIM);
#pragma unroll
    for (int di = 0; di < 3; di++) {
        int d = di * 16 + lm;
        int n0 = t0 + lkb * 4;
        float4 ov;
        ov.x = oa[di][0]; ov.y = oa[di][1]; ov.z = oa[di][2]; ov.w = oa[di][3];
        *(float4*)(o_scr + obase + (size_t)(d * NH + h) * NTOK + n0) = ov;
    }
}

// ---------------------------------------------------------------------------
// LayerNorm over rows of 384, write bf16. block 128, one row per block.
// ---------------------------------------------------------------------------
__global__ __launch_bounds__(128) void ln_kernel(
    const float* __restrict__ o, const float* __restrict__ gamma,
    const float* __restrict__ beta, u16* __restrict__ outbf)
{
    int row = blockIdx.x;
    const float* rp = o + (size_t)row * CDIM;
    int tid = threadIdx.x;
    float v0 = rp[tid], v1 = rp[tid + 128], v2 = rp[tid + 256];
    float s = v0 + v1 + v2;
    for (int m = 1; m < 64; m <<= 1) s += __shfl_xor(s, m, 64);
    __shared__ float red[2];
    if ((tid & 63) == 0) red[tid >> 6] = s;
    __syncthreads();
    float mean = (red[0] + red[1]) * (1.0f / CDIM);
    float d0 = v0 - mean, d1 = v1 - mean, d2 = v2 - mean;
    float qv = d0 * d0 + d1 * d1 + d2 * d2;
    for (int m = 1; m < 64; m <<= 1) qv += __shfl_xor(qv, m, 64);
    __shared__ float red2[2];
    if ((tid & 63) == 0) red2[tid >> 6] = qv;
    __syncthreads();
    float var = (red2[0] + red2[1]) * (1.0f / CDIM);
    float rstd = rsqrtf(var + 1e-5f);
    u16* op = outbf + (size_t)row * CDIM;
    op[tid]       = f2b(d0 * rstd * gamma[tid]       + beta[tid]);
    op[tid + 128] = f2b(d1 * rstd * gamma[tid + 128] + beta[tid + 128]);
    op[tid + 256] = f2b(d2 * rstd * gamma[tid + 256] + beta[tid + 256]);
}

// ---------------------------------------------------------------------------
extern "C" void kernel_launch(void* const* d_in, const int* in_sizes, int n_in,
                              void* d_out, int out_size, void* d_ws, size_t ws_size,
                              hipStream_t stream)
{
    (void)in_sizes; (void)n_in; (void)out_size; (void)ws_size;
    const float* x    = (const float*)d_in[0];
    const float* y    = (const float*)d_in[1];
    const float* Wq   = (const float*)d_in[2];
    const float* Wkv  = (const float*)d_in[3];
    const float* EF   = (const float*)d_in[4];
    const float* temp = (const float*)d_in[5];
    const float* gam  = (const float*)d_in[6];
    const float* bet  = (const float*)d_in[7];
    const float* w1   = (const float*)d_in[8];
    const float* b1   = (const float*)d_in[9];
    const float* w2   = (const float*)d_in[10];
    const float* b2   = (const float*)d_in[11];
    float* out = (float*)d_out;

    char* w = (char*)d_ws;
    size_t off = 0;
    auto alloc = [&](size_t nb) { size_t o = off; off += (nb + 255) & ~(size_t)255; return o; };
    u16*   xt_bf = (u16*)(w + alloc((size_t)BDIM * NTOK * CDIM * 2));
    u16*   x_bf  = (u16*)(w + alloc((size_t)BDIM * NTOK * CDIM * 2)); // reused as ln_bf
    u16*   q_bf  = (u16*)(w + alloc((size_t)BDIM * NTOK * CDIM * 2));
    u16*   Wqt   = (u16*)(w + alloc((size_t)CDIM * CDIM * 2));
    u16*   EFt   = (u16*)(w + alloc((size_t)PDIM * NTOK * 2));
    u16*   w1t   = (u16*)(w + alloc((size_t)1536 * CDIM * 2));
    u16*   w2t   = (u16*)(w + alloc((size_t)CDIM * 1536 * 2));
    u16*   Wkvt  = (u16*)(w + alloc((size_t)768 * CDIM * 2));
    float* gpart = (float*)(w + alloc((size_t)BDIM * NTOK * 1536 * 2)); // union w/ h1bf
    u16*   h1bf  = (u16*)gpart;
    u16*   Gt_bf = (u16*)(w + alloc((size_t)BDIM * PDIM * CDIM * 2));
    float* kpvpf = (float*)(w + alloc((size_t)BDIM * PDIM * 2 * CDIM * 4));
    float* pcs   = (float*)(w + alloc((size_t)16 * BDIM * CDIM * 4));
    float* css   = (float*)(w + alloc((size_t)BDIM * CDIM * 4));
    u16*   kps   = (u16*)(w + alloc((size_t)BDIM * NH * PDIM * HDIM * 2));
    u16*   vpb   = (u16*)(w + alloc((size_t)BDIM * NH * HDIM * PDIM * 2));
    float* o_scr = (float*)(w + alloc((size_t)BDIM * NTOK * CDIM * 4));
    u16*   ln_bf = x_bf;

    dim3 tb(32, 8, 1);
    transpose_cast<<<dim3(NTOK / 32, CDIM / 32, BDIM), tb, 0, stream>>>(x, xt_bf, x_bf, CDIM, NTOK);
    transpose_cast<<<dim3(CDIM / 32, CDIM / 32, 1), tb, 0, stream>>>(Wq, Wqt, nullptr, CDIM, CDIM);
    transpose_cast<<<dim3(PDIM / 32, NTOK / 32, 1), tb, 0, stream>>>(EF, EFt, nullptr, NTOK, PDIM);
    transpose_cast<<<dim3(1536 / 32, CDIM / 32, 1), tb, 0, stream>>>(w1, w1t, nullptr, CDIM, 1536);
    transpose_cast<<<dim3(CDIM / 32, 1536 / 32, 1), tb, 0, stream>>>(w2, w2t, nullptr, 1536, CDIM);
    transpose_cast<<<dim3(768 / 32, CDIM / 32, 1), tb, 0, stream>>>(Wkv, Wkvt, nullptr, CDIM, 768);

    // Gt partials: Gt[b][p][c] = sum_n EFt[p,n] * x_bf[b][c][n], split-K 16
    gemm_bt<4, 1><<<dim3(PDIM / 64, CDIM / 128, BDIM * 16), 256, 0, stream>>>(
        EFt, x_bf, PDIM, CDIM, NTOK, 0, (long)CDIM * NTOK, (long)PDIM * CDIM,
        gpart, nullptr, nullptr, nullptr, nullptr);
    gred<<<dim3((BDIM * PDIM * CDIM) / 256, 1, 1), 256, 0, stream>>>(gpart, Gt_bf);

    // q = xt @ Wq -> bf16 q_bf
    gemm_bt<5, 1><<<dim3(NTOK / 64, CDIM / 128, BDIM), 256, 0, stream>>>(
        xt_bf, Wqt, NTOK, CDIM, CDIM, (long)NTOK * CDIM, 0, (long)NTOK * CDIM,
        nullptr, nullptr, q_bf, nullptr, nullptr);

    colsumsq<<<dim3(CDIM / 128, 16, BDIM), 128, 0, stream>>>(q_bf, pcs);
    colsumred<<<dim3(6, 1, 1), 256, 0, stream>>>(pcs, css);

    // kpvp_t[b] = Gt_bf[b] @ Wkvt^T : [256, 768] f32
    gemm_bt<0, 1><<<dim3(PDIM / 64, 768 / 128, BDIM), 256, 0, stream>>>(
        Gt_bf, Wkvt, PDIM, 768, CDIM, (long)PDIM * CDIM, 0, (long)PDIM * 768,
        kpvpf, nullptr, nullptr, nullptr, nullptr);

    scalepack2<<<dim3((BDIM * PDIM * CDIM) / 256, 1, 1), 256, 0, stream>>>(
        kpvpf, css, temp, kps, vpb);

    attn_fused<<<dim3(NTOK / 64, NH, BDIM), 256, 0, stream>>>(q_bf, kps, vpb, o_scr);

    ln_kernel<<<dim3(BDIM * NTOK, 1, 1), 128, 0, stream>>>(o_scr, gam, bet, ln_bf);

    // MLP1: gelu(ln @ w1 + b1) -> bf16 [16384,1536]
    gemm_bt<1, 0><<<dim3((BDIM * NTOK) / 128, 1536 / 128, 1), 256, 0, stream>>>(
        ln_bf, w1t, BDIM * NTOK, 1536, CDIM, 0, 0, 0,
        nullptr, b1, h1bf, nullptr, nullptr);
    // MLP2: h1 @ w2 + b2 + y (transposed add) -> f32 out [B,C,N]
    gemm_bt<2, 1><<<dim3((BDIM * NTOK) / 64, CDIM / 128, 1), 256, 0, stream>>>(
        h1bf, w2t, BDIM * NTOK, CDIM, 1536, 0, 0, 0,
        nullptr, b2, nullptr, y, out);
}

// Round 7
// 221.457 us; speedup vs baseline: 1.0058x; 1.0058x over previous
//
#include <hip/hip_runtime.h>

#define NH 8
#define CDIM 384
#define HDIM 48
#define NTOK 4096
#define PDIM 256
#define BDIM 4

typedef unsigned short u16;
typedef unsigned int u32;
typedef __bf16 bf16x8 __attribute__((ext_vector_type(8)));
typedef float f32x4 __attribute__((ext_vector_type(4)));

__device__ __forceinline__ u16 f2b(float f) {
    u32 u = __float_as_uint(f);
    u = (u + 0x7fffu + ((u >> 16) & 1u)) >> 16;   // RNE bf16
    return (u16)u;
}
__device__ __forceinline__ float b2f(u16 u) {
    return __uint_as_float(((u32)u) << 16);
}

__device__ __forceinline__ bf16x8 bzero8() {
    bf16x8 v;
#pragma unroll
    for (int i = 0; i < 8; i++) v[i] = (__bf16)0.0f;
    return v;
}

__device__ __forceinline__ void gload16(const u16* g, u16* l) {
    __builtin_amdgcn_global_load_lds(
        (const __attribute__((address_space(1))) void*)g,
        (__attribute__((address_space(3))) void*)l, 16, 0, 0);
}

// tanh-form GELU, max abs err ~3e-4 vs exact erf form
__device__ __forceinline__ float gelu_f(float x) {
    float z = 0.7978845608028654f * (x + 0.044715f * x * x * x);
    float e = __expf(2.0f * z);
    float t = 1.0f - 2.0f / (e + 1.0f);
    return 0.5f * x * (1.0f + t);
}

// ---------------------------------------------------------------------------
// Batched transpose + cast: in f32 [Z,R,Cc] -> outT bf16 [Z,Cc,R]
// optional outC bf16 [Z,R,Cc]. block (32,8)
// ---------------------------------------------------------------------------
__global__ __launch_bounds__(256) void transpose_cast(
    const float* __restrict__ in, u16* __restrict__ outT, u16* __restrict__ outC,
    int R, int Cc)
{
    __shared__ float tile[32][33];
    int r0 = blockIdx.y * 32, c0 = blockIdx.x * 32;
    size_t zoff = (size_t)blockIdx.z * R * Cc;
    const float* inp = in + zoff;
    int tx = threadIdx.x, ty = threadIdx.y;
#pragma unroll
    for (int i = 0; i < 4; i++) {
        int r = r0 + ty + i * 8;
        float v = inp[(size_t)r * Cc + c0 + tx];
        tile[ty + i * 8][tx] = v;
        if (outC) outC[zoff + (size_t)r * Cc + c0 + tx] = f2b(v);
    }
    __syncthreads();
    u16* oT = outT + zoff;
#pragma unroll
    for (int i = 0; i < 4; i++) {
        int c = c0 + ty + i * 8;
        oT[(size_t)c * R + r0 + tx] = f2b(tile[tx][ty + i * 8]);
    }
}

// ---------------------------------------------------------------------------
// GEMM: C[M,N] = A[M,K](bf16,row) @ Bt[N,K](bf16,row)^T, f32 accum.
// Tile BMv x 128 (BMv = HALFM?64:128), BK=32, 4 waves, 16x16x32 MFMA.
// 3-deep LDS ring + counted vmcnt; ONE s_barrier per K-step.
// T2 LDS swizzle (both-sides, rule #21): global source chunk is permuted
// ch^=(r>>1)&3 (linear LDS dest via global_load_lds), reads apply the same
// involution -> even lanes spread over all 4 chunk slots (2-way, free)
// instead of 8-way same-bank-quad conflicts.
// EPI 0: f32 store; EPI 1: gelu->bf16; EPI 2: +bias+Y transposed f32 out;
// EPI 4: split-K partials; EPI 5: bf16 store with batch offset.
// ---------------------------------------------------------------------------
template <int EPI, int HALFM>
__global__ __launch_bounds__(256) void gemm_bt(
    const u16* __restrict__ A, const u16* __restrict__ Bt,
    int M, int Nn, int K, long sA, long sB, long sC,
    float* __restrict__ Cf, const float* __restrict__ bias,
    u16* __restrict__ Cbf, const float* __restrict__ Yin, float* __restrict__ Out)
{
    const int BMv = HALFM ? 64 : 128;
    const int MT  = HALFM ? 2 : 4;
    const int BK = 32, LP = 32;
    __shared__ u16 lsA[3][BMv * LP];
    __shared__ u16 lsB[3][128 * LP];
    const int tid = threadIdx.x;
    const int wave = tid >> 6, lane = tid & 63;
    const int lm = lane & 15, lkb = lane >> 4;
    const int bm = blockIdx.x, bn = blockIdx.y, bz = blockIdx.z;
    int bb = bz, ks = 0, ke = K;
    if (EPI == 4) { bb = bz >> 4; ks = (bz & 15) * (K >> 4); ke = ks + (K >> 4); }
    const u16* Ab = A + (size_t)bb * sA;
    const u16* Bb = Bt + (size_t)bb * sB;
    const int wm = (wave >> 1) * (HALFM ? 32 : 64), wn = (wave & 1) * 64;

    f32x4 acc[MT][4];
#pragma unroll
    for (int i = 0; i < MT; i++)
#pragma unroll
        for (int j = 0; j < 4; j++) acc[i][j] = f32x4{0.f, 0.f, 0.f, 0.f};

    // swizzled global source chunk: LDS chunk (r, c) holds global chunk c^((r>>1)&3)
    auto stage = [&](int k0, int c) {
        if (HALFM) {
            int cb = wave * 64;
            int q = cb + lane;
            int r = q >> 2, ch = (q & 3) ^ ((r >> 1) & 3);
            gload16(Ab + (size_t)(bm * BMv + r) * K + k0 + ch * 8, &lsA[c][cb * 8]);
        } else {
#pragma unroll
            for (int j = 0; j < 2; j++) {
                int cb = (j * 4 + wave) * 64;
                int q = cb + lane;
                int r = q >> 2, ch = (q & 3) ^ ((r >> 1) & 3);
                gload16(Ab + (size_t)(bm * BMv + r) * K + k0 + ch * 8, &lsA[c][cb * 8]);
            }
        }
#pragma unroll
        for (int j = 0; j < 2; j++) {
            int cb = (j * 4 + wave) * 64;
            int q = cb + lane;
            int r = q >> 2, ch = (q & 3) ^ ((r >> 1) & 3);
            gload16(Bb + (size_t)(bn * 128 + r) * K + k0 + ch * 8, &lsB[c][cb * 8]);
        }
    };
    // loads per stage per thread
    #define WAIT_LD() do { if (HALFM) asm volatile("s_waitcnt vmcnt(3)" ::: "memory"); \
                           else       asm volatile("s_waitcnt vmcnt(4)" ::: "memory"); } while (0)

    const int nt = (ke - ks) / BK;   // all launches have nt >= 8
    stage(ks, 0);
    stage(ks + BK, 1);
    WAIT_LD();                        // tile 0 complete (tile 1 in flight)
    __builtin_amdgcn_s_barrier();
    __builtin_amdgcn_sched_barrier(0);

    for (int t = 0; t < nt; ++t) {
        const int cur = t % 3;
        if (t + 2 < nt) stage(ks + (t + 2) * BK, (t + 2) % 3);
        bf16x8 af[MT], bfr[4];
#pragma unroll
        for (int m = 0; m < MT; m++) {
            int R = wm + m * 16 + lm;
            af[m] = *(const bf16x8*)&lsA[cur][R * LP + ((lkb ^ ((R >> 1) & 3)) * 8)];
        }
#pragma unroll
        for (int n = 0; n < 4; n++) {
            int R = wn + n * 16 + lm;
            bfr[n] = *(const bf16x8*)&lsB[cur][R * LP + ((lkb ^ ((R >> 1) & 3)) * 8)];
        }
#pragma unroll
        for (int mi = 0; mi < MT; mi++)
#pragma unroll
            for (int ni = 0; ni < 4; ni++)
                acc[mi][ni] = __builtin_amdgcn_mfma_f32_16x16x32_bf16(
                    af[mi], bfr[ni], acc[mi][ni], 0, 0, 0);
        if (t + 1 < nt) {
            __builtin_amdgcn_sched_barrier(0);
            if (t + 2 < nt) { WAIT_LD(); }
            else { asm volatile("s_waitcnt vmcnt(0)" ::: "memory"); }
            __builtin_amdgcn_s_barrier();
            __builtin_amdgcn_sched_barrier(0);
        }
    }
    #undef WAIT_LD

    if (EPI == 2) {
#pragma unroll
        for (int mi = 0; mi < MT; mi++)
#pragma unroll
            for (int ni = 0; ni < 4; ni++) {
                int m0 = bm * BMv + wm + mi * 16 + lkb * 4;
                int n = bn * 128 + wn + ni * 16 + lm;
                int b = m0 >> 12, tok = m0 & 4095;
                size_t oi = ((size_t)b * CDIM + n) * NTOK + tok;
                float4 yv = *(const float4*)(Yin + oi);
                float bv = bias[n];
                float4 ov;
                ov.x = acc[mi][ni][0] + bv + yv.x;
                ov.y = acc[mi][ni][1] + bv + yv.y;
                ov.z = acc[mi][ni][2] + bv + yv.z;
                ov.w = acc[mi][ni][3] + bv + yv.w;
                *(float4*)(Out + oi) = ov;
            }
    } else {
#pragma unroll
        for (int mi = 0; mi < MT; mi++)
#pragma unroll
            for (int ni = 0; ni < 4; ni++)
#pragma unroll
                for (int r = 0; r < 4; r++) {
                    int m = bm * BMv + wm + mi * 16 + lkb * 4 + r;
                    int n = bn * 128 + wn + ni * 16 + lm;
                    float v = acc[mi][ni][r];
                    if (EPI == 0) {
                        Cf[(size_t)bz * sC + (size_t)m * Nn + n] = v;
                    } else if (EPI == 1) {
                        Cbf[(size_t)m * Nn + n] = f2b(gelu_f(v + bias[n]));
                    } else if (EPI == 4) {
                        Cf[(size_t)bz * sC + (size_t)m * Nn + n] = v;
                    } else {  // EPI == 5
                        Cbf[(size_t)bz * sC + (size_t)m * Nn + n] = f2b(v);
                    }
                }
    }
}

// ---------------------------------------------------------------------------
// Reduce 16 split-K slices -> bf16 Gt [B, 256, 384]
// ---------------------------------------------------------------------------
__global__ __launch_bounds__(256) void gred(
    const float* __restrict__ part, u16* __restrict__ Gtb)
{
    int idx = blockIdx.x * 256 + threadIdx.x;      // over B*P*C
    int b = idx / (PDIM * CDIM);
    int e = idx % (PDIM * CDIM);
    float s = 0.f;
#pragma unroll
    for (int j = 0; j < 16; j++)
        s += part[((size_t)(b * 16 + j)) * (PDIM * CDIM) + e];
    Gtb[idx] = f2b(s);
}

// ---------------------------------------------------------------------------
// Column sum-of-squares of q_bf [B,N,C] over N (256-token chunks)
// ---------------------------------------------------------------------------
__global__ __launch_bounds__(128) void colsumsq(
    const u16* __restrict__ q, float* __restrict__ pcs)
{
    int c = blockIdx.x * 128 + threadIdx.x;
    int b = blockIdx.z;
    int chunk = blockIdx.y;
    const u16* qp = q + ((size_t)b * NTOK + chunk * 256) * CDIM + c;
    float s = 0.f;
#pragma unroll 4
    for (int i = 0; i < 256; i++) { float v = b2f(qp[(size_t)i * CDIM]); s += v * v; }
    pcs[(size_t)chunk * (BDIM * CDIM) + b * CDIM + c] = s;
}

__global__ __launch_bounds__(256) void colsumred(
    const float* __restrict__ pcs, float* __restrict__ css)
{
    int idx = blockIdx.x * 256 + threadIdx.x;
    if (idx < BDIM * CDIM) {
        float s = 0.f;
#pragma unroll
        for (int j = 0; j < 16; j++) s += pcs[(size_t)j * (BDIM * CDIM) + idx];
        css[idx] = s;
    }
}

// ---------------------------------------------------------------------------
// From kpvp_t [b, p, 0:384]=kp, [b, p, 384:768]=vp (f32):
// kps [bh, p, d] scaled bf16;  vpb [bh, d, p] bf16
// ---------------------------------------------------------------------------
__global__ __launch_bounds__(256) void scalepack2(
    const float* __restrict__ kpvp, const float* __restrict__ css,
    const float* __restrict__ temp, u16* __restrict__ kps, u16* __restrict__ vpb)
{
    int idx = blockIdx.x * 256 + threadIdx.x;      // over B*P*C
    int c = idx % CDIM;
    int t = idx / CDIM;
    int p = t & 255;
    int b = t >> 8;
    int h = c / HDIM, d = c % HDIM;
    const float* row = kpvp + ((size_t)b * PDIM + p) * (2 * CDIM);
    float kv = row[c];
    float vv = row[CDIM + c];
    float nrm = fmaxf(sqrtf(css[b * CDIM + c]), 1e-12f);
    float sc = temp[h] / nrm;
    int bh = b * NH + h;
    kps[((size_t)bh * PDIM + p) * HDIM + d] = f2b(kv * sc);
    vpb[((size_t)bh * HDIM + d) * PDIM + p] = f2b(vv);
}

// ---------------------------------------------------------------------------
// Fused attention: per (ntile of 64 tokens, h, b).
// ---------------------------------------------------------------------------
__global__ __launch_bounds__(256) void attn_fused(
    const u16* __restrict__ qbf, const u16* __restrict__ kps,
    const u16* __restrict__ vpb, float* __restrict__ o_scr)
{
    __shared__ u16 vp_l[48 * 264];   // [d][p] pad 256->264
    __shared__ u16 un[64 * 264];     // union: kp_l [256][56] then p_l [64][264]
    u16* kp_l = un;
    u16* p_l = un;

    int nt = blockIdx.x, h = blockIdx.y, b = blockIdx.z;
    int tid = threadIdx.x, wave = tid >> 6, lane = tid & 63;
    int lm = lane & 15, lkb = lane >> 4;
    const u16* kpsb = kps + (size_t)(b * NH + h) * PDIM * HDIM;
    const u16* vpbb = vpb + (size_t)(b * NH + h) * HDIM * PDIM;

    for (int i = tid; i < 1536; i += 256) {      // 256 rows x 6 uint4
        int row = i / 6, ch = i % 6;
        *(uint4*)&kp_l[row * 56 + ch * 8] = *(const uint4*)(kpsb + row * 48 + ch * 8);
    }
    for (int i = tid; i < 1536; i += 256) {      // 48 rows x 32 uint4
        int row = i / 32, ch = i % 32;
        *(uint4*)&vp_l[row * 264 + ch * 8] = *(const uint4*)(vpbb + row * 256 + ch * 8);
    }
    __syncthreads();

    int t0 = nt * 64 + wave * 16;
    const u16* qb = qbf + ((size_t)b * NTOK + t0 + lm) * CDIM + h * HDIM;
    bf16x8 a0 = *(const bf16x8*)(qb + lkb * 8);
    bf16x8 a1 = bzero8();
    if (lkb < 2) a1 = *(const bf16x8*)(qb + 32 + lkb * 8);

    f32x4 s[16];
#pragma unroll
    for (int pi = 0; pi < 16; pi++) {
        f32x4 acc = f32x4{0.f, 0.f, 0.f, 0.f};
        bf16x8 b0 = *(const bf16x8*)&kp_l[(pi * 16 + lm) * 56 + lkb * 8];
        acc = __builtin_amdgcn_mfma_f32_16x16x32_bf16(a0, b0, acc, 0, 0, 0);
        bf16x8 b1 = bzero8();
        if (lkb < 2) b1 = *(const bf16x8*)&kp_l[(pi * 16 + lm) * 56 + 32 + lkb * 8];
        acc = __builtin_amdgcn_mfma_f32_16x16x32_bf16(a1, b1, acc, 0, 0, 0);
        s[pi] = acc;
    }
    __syncthreads();   // all QK^T reads of kp_l done before p_l overwrites it

    // softmax over 256 cols
#pragma unroll
    for (int r = 0; r < 4; r++) {
        float mx = s[0][r];
#pragma unroll
        for (int pi = 1; pi < 16; pi++) mx = fmaxf(mx, s[pi][r]);
        for (int m = 1; m < 16; m <<= 1) mx = fmaxf(mx, __shfl_xor(mx, m, 64));
        float e[16];
        float sum = 0.f;
#pragma unroll
        for (int pi = 0; pi < 16; pi++) { e[pi] = __expf(s[pi][r] - mx); sum += e[pi]; }
        for (int m = 1; m < 16; m <<= 1) sum += __shfl_xor(sum, m, 64);
        float inv = 1.0f / sum;
        int tl = wave * 16 + lkb * 4 + r;
#pragma unroll
        for (int pi = 0; pi < 16; pi++)
            p_l[tl * 264 + pi * 16 + lm] = f2b(e[pi] * inv);
    }
    __syncthreads();

    // o = p @ vp^T : per wave 16 tokens x 48 d, K=256
    f32x4 oa[3];
#pragma unroll
    for (int di = 0; di < 3; di++) oa[di] = f32x4{0.f, 0.f, 0.f, 0.f};
#pragma unroll
    for (int ksl = 0; ksl < 8; ksl++) {
        bf16x8 pa = *(const bf16x8*)&p_l[(wave * 16 + lm) * 264 + ksl * 32 + lkb * 8];
#pragma unroll
        for (int di = 0; di < 3; di++) {
            bf16x8 vb = *(const bf16x8*)&vp_l[(di * 16 + lm) * 264 + ksl * 32 + lkb * 8];
            oa[di] = __builtin_amdgcn_mfma_f32_16x16x32_bf16(pa, vb, oa[di], 0, 0, 0);
        }
    }
    size_t obase = (size_t)b * ((size_t)NTOK * CDIM);
#pragma unroll
    for (int di = 0; di < 3; di++) {
        int d = di * 16 + lm;
        int n0 = t0 + lkb * 4;
        float4 ov;
        ov.x = oa[di][0]; ov.y = oa[di][1]; ov.z = oa[di][2]; ov.w = oa[di][3];
        *(float4*)(o_scr + obase + (size_t)(d * NH + h) * NTOK + n0) = ov;
    }
}

// ---------------------------------------------------------------------------
// LayerNorm over rows of 384, write bf16. block 128, one row per block.
// ---------------------------------------------------------------------------
__global__ __launch_bounds__(128) void ln_kernel(
    const float* __restrict__ o, const float* __restrict__ gamma,
    const float* __restrict__ beta, u16* __restrict__ outbf)
{
    int row = blockIdx.x;
    const float* rp = o + (size_t)row * CDIM;
    int tid = threadIdx.x;
    float v0 = rp[tid], v1 = rp[tid + 128], v2 = rp[tid + 256];
    float s = v0 + v1 + v2;
    for (int m = 1; m < 64; m <<= 1) s += __shfl_xor(s, m, 64);
    __shared__ float red[2];
    if ((tid & 63) == 0) red[tid >> 6] = s;
    __syncthreads();
    float mean = (red[0] + red[1]) * (1.0f / CDIM);
    float d0 = v0 - mean, d1 = v1 - mean, d2 = v2 - mean;
    float qv = d0 * d0 + d1 * d1 + d2 * d2;
    for (int m = 1; m < 64; m <<= 1) qv += __shfl_xor(qv, m, 64);
    __shared__ float red2[2];
    if ((tid & 63) == 0) red2[tid >> 6] = qv;
    __syncthreads();
    float var = (red2[0] + red2[1]) * (1.0f / CDIM);
    float rstd = rsqrtf(var + 1e-5f);
    u16* op = outbf + (size_t)row * CDIM;
    op[tid]       = f2b(d0 * rstd * gamma[tid]       + beta[tid]);
    op[tid + 128] = f2b(d1 * rstd * gamma[tid + 128] + beta[tid + 128]);
    op[tid + 256] = f2b(d2 * rstd * gamma[tid + 256] + beta[tid + 256]);
}

// ---------------------------------------------------------------------------
extern "C" void kernel_launch(void* const* d_in, const int* in_sizes, int n_in,
                              void* d_out, int out_size, void* d_ws, size_t ws_size,
                              hipStream_t stream)
{
    (void)in_sizes; (void)n_in; (void)out_size; (void)ws_size;
    const float* x    = (const float*)d_in[0];
    const float* y    = (const float*)d_in[1];
    const float* Wq   = (const float*)d_in[2];
    const float* Wkv  = (const float*)d_in[3];
    const float* EF   = (const float*)d_in[4];
    const float* temp = (const float*)d_in[5];
    const float* gam  = (const float*)d_in[6];
    const float* bet  = (const float*)d_in[7];
    const float* w1   = (const float*)d_in[8];
    const float* b1   = (const float*)d_in[9];
    const float* w2   = (const float*)d_in[10];
    const float* b2   = (const float*)d_in[11];
    float* out = (float*)d_out;

    char* w = (char*)d_ws;
    size_t off = 0;
    auto alloc = [&](size_t nb) { size_t o = off; off += (nb + 255) & ~(size_t)255; return o; };
    u16*   xt_bf = (u16*)(w + alloc((size_t)BDIM * NTOK * CDIM * 2));
    u16*   x_bf  = (u16*)(w + alloc((size_t)BDIM * NTOK * CDIM * 2)); // reused as ln_bf
    u16*   q_bf  = (u16*)(w + alloc((size_t)BDIM * NTOK * CDIM * 2));
    u16*   Wqt   = (u16*)(w + alloc((size_t)CDIM * CDIM * 2));
    u16*   EFt   = (u16*)(w + alloc((size_t)PDIM * NTOK * 2));
    u16*   w1t   = (u16*)(w + alloc((size_t)1536 * CDIM * 2));
    u16*   w2t   = (u16*)(w + alloc((size_t)CDIM * 1536 * 2));
    u16*   Wkvt  = (u16*)(w + alloc((size_t)768 * CDIM * 2));
    float* gpart = (float*)(w + alloc((size_t)BDIM * NTOK * 1536 * 2)); // union w/ h1bf
    u16*   h1bf  = (u16*)gpart;
    u16*   Gt_bf = (u16*)(w + alloc((size_t)BDIM * PDIM * CDIM * 2));
    float* kpvpf = (float*)(w + alloc((size_t)BDIM * PDIM * 2 * CDIM * 4));
    float* pcs   = (float*)(w + alloc((size_t)16 * BDIM * CDIM * 4));
    float* css   = (float*)(w + alloc((size_t)BDIM * CDIM * 4));
    u16*   kps   = (u16*)(w + alloc((size_t)BDIM * NH * PDIM * HDIM * 2));
    u16*   vpb   = (u16*)(w + alloc((size_t)BDIM * NH * HDIM * PDIM * 2));
    float* o_scr = (float*)(w + alloc((size_t)BDIM * NTOK * CDIM * 4));
    u16*   ln_bf = x_bf;

    dim3 tb(32, 8, 1);
    transpose_cast<<<dim3(NTOK / 32, CDIM / 32, BDIM), tb, 0, stream>>>(x, xt_bf, x_bf, CDIM, NTOK);
    transpose_cast<<<dim3(CDIM / 32, CDIM / 32, 1), tb, 0, stream>>>(Wq, Wqt, nullptr, CDIM, CDIM);
    transpose_cast<<<dim3(PDIM / 32, NTOK / 32, 1), tb, 0, stream>>>(EF, EFt, nullptr, NTOK, PDIM);
    transpose_cast<<<dim3(1536 / 32, CDIM / 32, 1), tb, 0, stream>>>(w1, w1t, nullptr, CDIM, 1536);
    transpose_cast<<<dim3(CDIM / 32, 1536 / 32, 1), tb, 0, stream>>>(w2, w2t, nullptr, 1536, CDIM);
    transpose_cast<<<dim3(768 / 32, CDIM / 32, 1), tb, 0, stream>>>(Wkv, Wkvt, nullptr, CDIM, 768);

    // Gt partials: Gt[b][p][c] = sum_n EFt[p,n] * x_bf[b][c][n], split-K 16
    gemm_bt<4, 1><<<dim3(PDIM / 64, CDIM / 128, BDIM * 16), 256, 0, stream>>>(
        EFt, x_bf, PDIM, CDIM, NTOK, 0, (long)CDIM * NTOK, (long)PDIM * CDIM,
        gpart, nullptr, nullptr, nullptr, nullptr);
    gred<<<dim3((BDIM * PDIM * CDIM) / 256, 1, 1), 256, 0, stream>>>(gpart, Gt_bf);

    // q = xt @ Wq -> bf16 q_bf
    gemm_bt<5, 1><<<dim3(NTOK / 64, CDIM / 128, BDIM), 256, 0, stream>>>(
        xt_bf, Wqt, NTOK, CDIM, CDIM, (long)NTOK * CDIM, 0, (long)NTOK * CDIM,
        nullptr, nullptr, q_bf, nullptr, nullptr);

    colsumsq<<<dim3(CDIM / 128, 16, BDIM), 128, 0, stream>>>(q_bf, pcs);
    colsumred<<<dim3(6, 1, 1), 256, 0, stream>>>(pcs, css);

    // kpvp_t[b] = Gt_bf[b] @ Wkvt^T : [256, 768] f32
    gemm_bt<0, 1><<<dim3(PDIM / 64, 768 / 128, BDIM), 256, 0, stream>>>(
        Gt_bf, Wkvt, PDIM, 768, CDIM, (long)PDIM * CDIM, 0, (long)PDIM * 768,
        kpvpf, nullptr, nullptr, nullptr, nullptr);

    scalepack2<<<dim3((BDIM * PDIM * CDIM) / 256, 1, 1), 256, 0, stream>>>(
        kpvpf, css, temp, kps, vpb);

    attn_fused<<<dim3(NTOK / 64, NH, BDIM), 256, 0, stream>>>(q_bf, kps, vpb, o_scr);

    ln_kernel<<<dim3(BDIM * NTOK, 1, 1), 128, 0, stream>>>(o_scr, gam, bet, ln_bf);

    // MLP1: gelu(ln @ w1 + b1) -> bf16 [16384,1536]
    gemm_bt<1, 0><<<dim3((BDIM * NTOK) / 128, 1536 / 128, 1), 256, 0, stream>>>(
        ln_bf, w1t, BDIM * NTOK, 1536, CDIM, 0, 0, 0,
        nullptr, b1, h1bf, nullptr, nullptr);
    // MLP2: h1 @ w2 + b2 + y (transposed add) -> f32 out [B,C,N]
    gemm_bt<2, 1><<<dim3((BDIM * NTOK) / 64, CDIM / 128, 1), 256, 0, stream>>>(
        h1bf, w2t, BDIM * NTOK, CDIM, 1536, 0, 0, 0,
        nullptr, b2, nullptr, y, out);
}